// Round 5
// baseline (108.625 us; speedup 1.0000x reference)
//
#include <hip/hip_runtime.h>
#include <hip/hip_bf16.h>

#define B_    8
#define N_    9225
#define M_    4096
#define K_    32
#define HID_  64
#define DOUT_ 16

typedef __attribute__((ext_vector_type(8))) short short8;
typedef __attribute__((ext_vector_type(4))) float floatx4;
typedef __attribute__((ext_vector_type(2))) float f32x2;

static __device__ __forceinline__ short f2bf(float f) {
    __hip_bfloat16 h = __float2bfloat16(f);
    return __builtin_bit_cast(short, h);
}
static __device__ __forceinline__ float bf2f(short s) {
    unsigned u = ((unsigned)(unsigned short)s) << 16;
    return __builtin_bit_cast(float, u);
}
static __device__ __forceinline__ f32x2 splat2(float v) { return (f32x2){v, v}; }

// Sum over each 16-lane DPP row via row_shr tree; lane (row*16+15) holds the sum.
static __device__ __forceinline__ float row16_sum(float v) {
    int t;
    t = __builtin_amdgcn_update_dpp(0, __builtin_bit_cast(int, v), 0x111, 0xF, 0xF, true);
    v += __builtin_bit_cast(float, t);
    t = __builtin_amdgcn_update_dpp(0, __builtin_bit_cast(int, v), 0x112, 0xF, 0xF, true);
    v += __builtin_bit_cast(float, t);
    t = __builtin_amdgcn_update_dpp(0, __builtin_bit_cast(int, v), 0x114, 0xF, 0xF, true);
    v += __builtin_bit_cast(float, t);
    t = __builtin_amdgcn_update_dpp(0, __builtin_bit_cast(int, v), 0x118, 0xF, 0xF, true);
    v += __builtin_bit_cast(float, t);
    return v;
}

// Packed-Pade gelu (R13-validated, absmax 0.0625): tanh via Pade(5,4),
// f32x2 throughout, 1 transcendental (rcp) per element.
static __device__ __forceinline__ f32x2 gelu2(f32x2 x) {
    const f32x2 xsq = x * x;
    const f32x2 t   = __builtin_elementwise_fma(xsq, splat2(0.035677408f), splat2(0.79788456f));
    const f32x2 z   = x * t;
    const f32x2 u   = z * z;
    const f32x2 a   = u + splat2(105.0f);
    const f32x2 nin = __builtin_elementwise_fma(u, a, splat2(945.0f));
    const f32x2 num = z * nin;
    const f32x2 bq  = __builtin_elementwise_fma(u, splat2(15.0f), splat2(420.0f));
    const f32x2 den = __builtin_elementwise_fma(u, bq, splat2(945.0f));
    const f32x2 r   = { __builtin_amdgcn_rcpf(den[0]), __builtin_amdgcn_rcpf(den[1]) };
    f32x2 th = num * r;
    th = __builtin_elementwise_min(__builtin_elementwise_max(th, splat2(-1.0f)), splat2(1.0f));
    const f32x2 hx = x * splat2(0.5f);
    return __builtin_elementwise_fma(hx, th, hx);
}

// Prologue: fw[i][c] = f_y[i][c] * w[i]. Removes the per-phase w gather
// entirely (same index as f_y, same product associativity as acc*(fv*s)).
// 4.7 MB in d_ws, coalesced 64B/thread.
__global__ __launch_bounds__(256) void pack_fw(
    const float* __restrict__ f_y, const float* __restrict__ w,
    float* __restrict__ fw)
{
    const int i = blockIdx.x * 256 + threadIdx.x;
    if (i < B_ * N_) {
        const float s = w[i];
        const floatx4* src = (const floatx4*)(f_y + (size_t)i * 16);
        floatx4* dst = (floatx4*)(fw + (size_t)i * 16);
        #pragma unroll
        for (int j = 0; j < 4; ++j) dst[j] = src[j] * s;
    }
}

// R16: scattered-address attack, stage 2. R15 (addresses 192->128/phase) gave
// the first movement in 5 rounds (it_kernel 42-44 -> <39.6us) after VALU/
// occupancy/VGPR/MFMA variations all pinned -- address throughput is the
// binding resource. This round: 128 -> 80 addrs/phase.
//  (1) w pre-multiplied into fw (prologue): w-gather gone; validity becomes
//      a 1/0 multiplier on fv.
//  (2) y-gather exec-masked to q==0 (masked lanes issue no requests): 64->16
//      addrs. q!=0 lanes' B-frag slots hit A==0 (R14-validated harmless).
//  (3) everything else identical to R15 (zero LDS/barriers, 4 rows/wave,
//      4-deep pipeline, packed-Pade gelu, hi/lo k-packed layer-1, XCD pin).
__global__ __launch_bounds__(256, 4) void it_kernel(
    const float* __restrict__ y,
    const float* __restrict__ x,
    const float* __restrict__ f_y,
    const float* __restrict__ weights,
    const float* __restrict__ W1,   // [4][64] row-major
    const float* __restrict__ b1,   // [64]
    const float* __restrict__ W2,   // [64][16] row-major
    const float* __restrict__ b2,   // [16]
    const int*   __restrict__ nbr,  // [B][M][K] int32
    const float* __restrict__ fw,   // packed f_y*w or null
    const int    packed,
    float*       __restrict__ out)  // [B][M][16]
{
    const int tid  = threadIdx.x;
    const int lane = tid & 63;
    const int q    = lane >> 4;    // quad 0..3
    const int nlo  = lane & 15;
    const bool q0  = (q == 0);

    const int blk   = blockIdx.x;
    const int batch = blk & 7;          // XCD pin (round-robin heuristic)
    const int pblk  = blk >> 3;         // 0..255 within batch
    const int wid   = tid >> 6;         // wave 0..3
    const int row0  = __builtin_amdgcn_readfirstlane(batch * M_ + pblk * 16 + wid * 4);
    const int bbase = batch * N_;

    // ---- W1^T A-fragments, hi/lo k-packed (R14-validated) ----
    short8 w1h[4];
    #pragma unroll
    for (int t = 0; t < 4; ++t) {
        #pragma unroll
        for (int jj = 0; jj < 4; ++jj) {
            const float wv = W1[jj * HID_ + t * 16 + nlo];
            const short b  = q0 ? f2bf(wv) : (short)0;
            w1h[t][jj]     = b;
            w1h[t][jj + 4] = b;
        }
    }

    // ---- W2 A-fragment with layer-1-layout re-index (R13-validated) ----
    short8 w2f[2];
    #pragma unroll
    for (int ch = 0; ch < 2; ++ch)
        #pragma unroll
        for (int jj = 0; jj < 8; ++jj) {
            const int H = (ch * 2 + (jj >> 2)) * 16 + q * 4 + (jj & 3);
            w2f[ch][jj] = f2bf(W2[H * DOUT_ + nlo]);
        }

    // ---- biases in VGPRs (zero LDS, zero barriers) ----
    floatx4 b1r[4];
    #pragma unroll
    for (int t = 0; t < 4; ++t)
        b1r[t] = *(const floatx4*)(b1 + t * 16 + q * 4);
    const floatx4 b2r = *(const floatx4*)(b2 + q * 4);

    // ---- per-row x hi/lo bf16 (4 rows) ----
    short xh[8], xl[8];
    #pragma unroll
    for (int it = 0; it < 4; ++it) {
        const float2 xv = *(const float2*)(x + (size_t)(row0 + it) * 2);
        const short h0 = f2bf(xv.x); const short l0 = f2bf(xv.x - bf2f(h0));
        const short h1 = f2bf(xv.y); const short l1 = f2bf(xv.y - bf2f(h1));
        xh[it * 2] = h0; xh[it * 2 + 1] = h1;
        xl[it * 2] = l0; xl[it * 2 + 1] = l1;
    }

    // ---- neighbor indices for all 8 phases issued up front ----
    int raw[8];
    #pragma unroll
    for (int ph = 0; ph < 8; ++ph) {
        const int it = ph >> 1, h = ph & 1;
        raw[ph] = nbr[(size_t)(row0 + it) * K_ + h * 16 + nlo];
    }

    // ---- gathers: 1 full wave-load (fw) + 1 q0-masked 8B load (y) per
    //      phase, pipelined 4 deep. yv2 on q!=0 lanes is uninit/garbage ->
    //      feeds only A==0 B-frag slots (harmless). ----
    float2 yv2[8]; floatx4 fv[8];
    #define GATH(P) { \
        const int rv  = raw[P]; \
        const int bn  = bbase + (rv >= 0 ? rv : 0); \
        if (packed) { \
            fv[P] = *(const floatx4*)(fw + (size_t)bn * 16 + q * 4); \
        } else { \
            const floatx4 tf = *(const floatx4*)(f_y + (size_t)bn * 16 + q * 4); \
            fv[P] = tf * weights[bn]; \
        } \
        if (q0) yv2[P] = *(const float2*)(y + (size_t)bn * 2); \
    }
    GATH(0); GATH(1); GATH(2); GATH(3);

    float partial[4] = {0.f, 0.f, 0.f, 0.f};
    #pragma unroll
    for (int ph = 0; ph < 8; ++ph) {
        if (ph + 4 < 8) GATH(ph + 4);
        const int it = ph >> 1;

        // ---- input B-fragment, hi at k=0..3, lo at k=4..7 (A zero elsewhere) ----
        const float y0 = yv2[ph].x, y1 = yv2[ph].y;
        const short yh0 = f2bf(y0); const short yl0 = f2bf(y0 - bf2f(yh0));
        const short yh1 = f2bf(y1); const short yl1 = f2bf(y1 - bf2f(yh1));
        const short8 bfull = { yh0, yh1, xh[it * 2], xh[it * 2 + 1],
                               yl0, yl1, xl[it * 2], xl[it * 2 + 1] };

        // ---- layer 1: one MFMA per 16-hid tile (hi+lo k-packed) ----
        floatx4 a1[4];
        #pragma unroll
        for (int t = 0; t < 4; ++t) {
            a1[t] = b1r[t];
            a1[t] = __builtin_amdgcn_mfma_f32_16x16x32_bf16(w1h[t], bfull, a1[t], 0, 0, 0);
        }

        // ---- gelu (packed) + pack to bf16 B-frag slots ----
        short hv[16];
        #pragma unroll
        for (int t = 0; t < 4; ++t) {
            const f32x2 g01 = gelu2((f32x2){a1[t][0], a1[t][1]});
            const f32x2 g23 = gelu2((f32x2){a1[t][2], a1[t][3]});
            hv[t * 4 + 0] = f2bf(g01[0]); hv[t * 4 + 1] = f2bf(g01[1]);
            hv[t * 4 + 2] = f2bf(g23[0]); hv[t * 4 + 3] = f2bf(g23[1]);
        }
        const short8 hf0 = {hv[0], hv[1], hv[2],  hv[3],  hv[4],  hv[5],  hv[6],  hv[7]};
        const short8 hf1 = {hv[8], hv[9], hv[10], hv[11], hv[12], hv[13], hv[14], hv[15]};

        // ---- layer 2: kval[c][elem] = W2^T . h + b2 ----
        floatx4 acc = b2r;
        acc = __builtin_amdgcn_mfma_f32_16x16x32_bf16(w2f[0], hf0, acc, 0, 0, 0);
        acc = __builtin_amdgcn_mfma_f32_16x16x32_bf16(w2f[1], hf1, acc, 0, 0, 0);

        // validity as 1/0 multiplier (w is already folded into fv)
        const float vm = (raw[ph] >= 0) ? 1.0f : 0.0f;
        const floatx4 fvp = fv[ph];
        #pragma unroll
        for (int r = 0; r < 4; ++r)
            partial[r] = fmaf(acc[r], fvp[r] * vm, partial[r]);

        if (ph & 1) {   // finished a row: reduce over 16 elem-lanes, store
            #pragma unroll
            for (int r = 0; r < 4; ++r) partial[r] = row16_sum(partial[r]);
            if (nlo == 15) {
                floatx4 o = {partial[0], partial[1], partial[2], partial[3]};
                *(floatx4*)(out + (size_t)(row0 + it) * DOUT_ + q * 4) = o;
            }
            #pragma unroll
            for (int r = 0; r < 4; ++r) partial[r] = 0.f;
        }
    }
    #undef GATH
}

extern "C" void kernel_launch(void* const* d_in, const int* in_sizes, int n_in,
                              void* d_out, int out_size, void* d_ws, size_t ws_size,
                              hipStream_t stream) {
    const float* y   = (const float*)d_in[0];
    const float* x   = (const float*)d_in[1];
    const float* f_y = (const float*)d_in[2];
    const float* w   = (const float*)d_in[3];
    const float* W1  = (const float*)d_in[4];
    const float* b1  = (const float*)d_in[5];
    const float* W2  = (const float*)d_in[6];
    const float* b2  = (const float*)d_in[7];
    const int*   nbr = (const int*)d_in[8];
    float* out = (float*)d_out;

    const size_t need = (size_t)B_ * N_ * DOUT_ * sizeof(float);
    const int packed = (d_ws != nullptr && ws_size >= need) ? 1 : 0;
    float* fw = (float*)d_ws;
    if (packed) {
        dim3 pgrid((B_ * N_ + 255) / 256), pblock(256);
        hipLaunchKernelGGL(pack_fw, pgrid, pblock, 0, stream, f_y, w, fw);
    }

    // 2048 blocks: 256 per batch (16 rows/block), batch = blk & 7 -> XCD pin
    dim3 grid(B_ * M_ / 16), block(256);
    hipLaunchKernelGGL(it_kernel, grid, block, 0, stream,
                       y, x, f_y, w, W1, b1, W2, b2, nbr, fw, packed, out);
}

// Round 6
// 106.023 us; speedup vs baseline: 1.0245x; 1.0245x over previous
//
#include <hip/hip_runtime.h>
#include <hip/hip_bf16.h>

#define B_    8
#define N_    9225
#define M_    4096
#define K_    32
#define HID_  64
#define DOUT_ 16

typedef __attribute__((ext_vector_type(8))) short short8;
typedef __attribute__((ext_vector_type(4))) float floatx4;
typedef __attribute__((ext_vector_type(2))) float f32x2;

static __device__ __forceinline__ short f2bf(float f) {
    __hip_bfloat16 h = __float2bfloat16(f);
    return __builtin_bit_cast(short, h);
}
static __device__ __forceinline__ float bf2f(short s) {
    unsigned u = ((unsigned)(unsigned short)s) << 16;
    return __builtin_bit_cast(float, u);
}
static __device__ __forceinline__ f32x2 splat2(float v) { return (f32x2){v, v}; }

// Sum over each 16-lane DPP row via row_shr tree; lane (row*16+15) holds the sum.
static __device__ __forceinline__ float row16_sum(float v) {
    int t;
    t = __builtin_amdgcn_update_dpp(0, __builtin_bit_cast(int, v), 0x111, 0xF, 0xF, true);
    v += __builtin_bit_cast(float, t);
    t = __builtin_amdgcn_update_dpp(0, __builtin_bit_cast(int, v), 0x112, 0xF, 0xF, true);
    v += __builtin_bit_cast(float, t);
    t = __builtin_amdgcn_update_dpp(0, __builtin_bit_cast(int, v), 0x114, 0xF, 0xF, true);
    v += __builtin_bit_cast(float, t);
    t = __builtin_amdgcn_update_dpp(0, __builtin_bit_cast(int, v), 0x118, 0xF, 0xF, true);
    v += __builtin_bit_cast(float, t);
    return v;
}

// Packed-Pade gelu (R13-validated, absmax 0.0625): tanh via Pade(5,4),
// f32x2 throughout, 1 transcendental (rcp) per element.
static __device__ __forceinline__ f32x2 gelu2(f32x2 x) {
    const f32x2 xsq = x * x;
    const f32x2 t   = __builtin_elementwise_fma(xsq, splat2(0.035677408f), splat2(0.79788456f));
    const f32x2 z   = x * t;
    const f32x2 u   = z * z;
    const f32x2 a   = u + splat2(105.0f);
    const f32x2 nin = __builtin_elementwise_fma(u, a, splat2(945.0f));
    const f32x2 num = z * nin;
    const f32x2 bq  = __builtin_elementwise_fma(u, splat2(15.0f), splat2(420.0f));
    const f32x2 den = __builtin_elementwise_fma(u, bq, splat2(945.0f));
    const f32x2 r   = { __builtin_amdgcn_rcpf(den[0]), __builtin_amdgcn_rcpf(den[1]) };
    f32x2 th = num * r;
    th = __builtin_elementwise_min(__builtin_elementwise_max(th, splat2(-1.0f)), splat2(1.0f));
    const f32x2 hx = x * splat2(0.5f);
    return __builtin_elementwise_fma(hx, th, hx);
}

// R17: single-dispatch ablation. R16 (addrs 128->80/phase) moved the bench
// by +0.8us (noise) -> the scattered-address model is weakened; R15's gain
// re-attributed to barrier removal + wave halving. New suspect: the prologue
// dispatch itself (launch+gap ~2-5us in the timed stream) offsets it_kernel
// gains. This round: NO prologue kernels; w gathered per-lane again
// (s = vld ? w[bn] : 0, the R13/R14-validated fold). Everything else frozen
// from R16: zero LDS/barriers, 4 rows/wave, 4-deep prefetch, q0-masked
// y-gather (now ZERO-INITIALIZED: stale q!=0 regs could be NaN and MFMA
// propagates 0*NaN), packed-Pade gelu, hi/lo k-packed layer-1, XCD pin.
// Outcomes: bench ~103-106 -> prologue overhead confirmed, keep 1 dispatch;
// ~111+ -> addresses matter, revert to packing; 107-109 -> null, attack VALU.
__global__ __launch_bounds__(256, 4) void it_kernel(
    const float* __restrict__ y,
    const float* __restrict__ x,
    const float* __restrict__ f_y,
    const float* __restrict__ weights,
    const float* __restrict__ W1,   // [4][64] row-major
    const float* __restrict__ b1,   // [64]
    const float* __restrict__ W2,   // [64][16] row-major
    const float* __restrict__ b2,   // [16]
    const int*   __restrict__ nbr,  // [B][M][K] int32
    float*       __restrict__ out)  // [B][M][16]
{
    const int tid  = threadIdx.x;
    const int lane = tid & 63;
    const int q    = lane >> 4;    // quad 0..3
    const int nlo  = lane & 15;
    const bool q0  = (q == 0);

    const int blk   = blockIdx.x;
    const int batch = blk & 7;          // XCD pin (round-robin heuristic)
    const int pblk  = blk >> 3;         // 0..255 within batch
    const int wid   = tid >> 6;         // wave 0..3
    const int row0  = __builtin_amdgcn_readfirstlane(batch * M_ + pblk * 16 + wid * 4);
    const int bbase = batch * N_;

    // ---- W1^T A-fragments, hi/lo k-packed (R14-validated) ----
    short8 w1h[4];
    #pragma unroll
    for (int t = 0; t < 4; ++t) {
        #pragma unroll
        for (int jj = 0; jj < 4; ++jj) {
            const float wv = W1[jj * HID_ + t * 16 + nlo];
            const short b  = q0 ? f2bf(wv) : (short)0;
            w1h[t][jj]     = b;
            w1h[t][jj + 4] = b;
        }
    }

    // ---- W2 A-fragment with layer-1-layout re-index (R13-validated) ----
    short8 w2f[2];
    #pragma unroll
    for (int ch = 0; ch < 2; ++ch)
        #pragma unroll
        for (int jj = 0; jj < 8; ++jj) {
            const int H = (ch * 2 + (jj >> 2)) * 16 + q * 4 + (jj & 3);
            w2f[ch][jj] = f2bf(W2[H * DOUT_ + nlo]);
        }

    // ---- biases in VGPRs (zero LDS, zero barriers) ----
    floatx4 b1r[4];
    #pragma unroll
    for (int t = 0; t < 4; ++t)
        b1r[t] = *(const floatx4*)(b1 + t * 16 + q * 4);
    const floatx4 b2r = *(const floatx4*)(b2 + q * 4);

    // ---- per-row x hi/lo bf16 (4 rows) ----
    short xh[8], xl[8];
    #pragma unroll
    for (int it = 0; it < 4; ++it) {
        const float2 xv = *(const float2*)(x + (size_t)(row0 + it) * 2);
        const short h0 = f2bf(xv.x); const short l0 = f2bf(xv.x - bf2f(h0));
        const short h1 = f2bf(xv.y); const short l1 = f2bf(xv.y - bf2f(h1));
        xh[it * 2] = h0; xh[it * 2 + 1] = h1;
        xl[it * 2] = l0; xl[it * 2 + 1] = l1;
    }

    // ---- neighbor indices for all 8 phases issued up front ----
    int raw[8];
    #pragma unroll
    for (int ph = 0; ph < 8; ++ph) {
        const int it = ph >> 1, h = ph & 1;
        raw[ph] = nbr[(size_t)(row0 + it) * K_ + h * 16 + nlo];
    }

    // ---- gathers: f_y (full wave) + w (full wave) + y (q0-masked, 16 addrs)
    //      per phase, pipelined 4 deep. yv2 zero-initialized so masked-off
    //      lanes contribute exact 0 (never stale-NaN) to the A==0 slots. ----
    float2 yv2[8]; float sw[8]; floatx4 fv[8];
    #pragma unroll
    for (int i = 0; i < 8; ++i) yv2[i] = (float2){0.0f, 0.0f};
    #define GATH(P) { \
        const int rv  = raw[P]; \
        const int vld = rv >= 0; \
        const int bn  = bbase + (vld ? rv : 0); \
        fv[P] = *(const floatx4*)(f_y + (size_t)bn * 16 + q * 4); \
        const float wv_ = weights[bn]; \
        sw[P] = vld ? wv_ : 0.0f; \
        if (q0) yv2[P] = *(const float2*)(y + (size_t)bn * 2); \
    }
    GATH(0); GATH(1); GATH(2); GATH(3);

    float partial[4] = {0.f, 0.f, 0.f, 0.f};
    #pragma unroll
    for (int ph = 0; ph < 8; ++ph) {
        if (ph + 4 < 8) GATH(ph + 4);
        const int it = ph >> 1;

        // ---- input B-fragment, hi at k=0..3, lo at k=4..7 (A zero elsewhere) ----
        const float y0 = yv2[ph].x, y1 = yv2[ph].y;
        const short yh0 = f2bf(y0); const short yl0 = f2bf(y0 - bf2f(yh0));
        const short yh1 = f2bf(y1); const short yl1 = f2bf(y1 - bf2f(yh1));
        const short8 bfull = { yh0, yh1, xh[it * 2], xh[it * 2 + 1],
                               yl0, yl1, xl[it * 2], xl[it * 2 + 1] };

        // ---- layer 1: one MFMA per 16-hid tile (hi+lo k-packed) ----
        floatx4 a1[4];
        #pragma unroll
        for (int t = 0; t < 4; ++t) {
            a1[t] = b1r[t];
            a1[t] = __builtin_amdgcn_mfma_f32_16x16x32_bf16(w1h[t], bfull, a1[t], 0, 0, 0);
        }

        // ---- gelu (packed) + pack to bf16 B-frag slots ----
        short hv[16];
        #pragma unroll
        for (int t = 0; t < 4; ++t) {
            const f32x2 g01 = gelu2((f32x2){a1[t][0], a1[t][1]});
            const f32x2 g23 = gelu2((f32x2){a1[t][2], a1[t][3]});
            hv[t * 4 + 0] = f2bf(g01[0]); hv[t * 4 + 1] = f2bf(g01[1]);
            hv[t * 4 + 2] = f2bf(g23[0]); hv[t * 4 + 3] = f2bf(g23[1]);
        }
        const short8 hf0 = {hv[0], hv[1], hv[2],  hv[3],  hv[4],  hv[5],  hv[6],  hv[7]};
        const short8 hf1 = {hv[8], hv[9], hv[10], hv[11], hv[12], hv[13], hv[14], hv[15]};

        // ---- layer 2: kval[c][elem] = W2^T . h + b2 ----
        floatx4 acc = b2r;
        acc = __builtin_amdgcn_mfma_f32_16x16x32_bf16(w2f[0], hf0, acc, 0, 0, 0);
        acc = __builtin_amdgcn_mfma_f32_16x16x32_bf16(w2f[1], hf1, acc, 0, 0, 0);

        const floatx4 fvp = fv[ph];
        const float   s   = sw[ph];          // 0 for invalid neighbors
        #pragma unroll
        for (int r = 0; r < 4; ++r)
            partial[r] = fmaf(acc[r], fvp[r] * s, partial[r]);

        if (ph & 1) {   // finished a row: reduce over 16 elem-lanes, store
            #pragma unroll
            for (int r = 0; r < 4; ++r) partial[r] = row16_sum(partial[r]);
            if (nlo == 15) {
                floatx4 o = {partial[0], partial[1], partial[2], partial[3]};
                *(floatx4*)(out + (size_t)(row0 + it) * DOUT_ + q * 4) = o;
            }
            #pragma unroll
            for (int r = 0; r < 4; ++r) partial[r] = 0.f;
        }
    }
    #undef GATH
}

extern "C" void kernel_launch(void* const* d_in, const int* in_sizes, int n_in,
                              void* d_out, int out_size, void* d_ws, size_t ws_size,
                              hipStream_t stream) {
    const float* y   = (const float*)d_in[0];
    const float* x   = (const float*)d_in[1];
    const float* f_y = (const float*)d_in[2];
    const float* w   = (const float*)d_in[3];
    const float* W1  = (const float*)d_in[4];
    const float* b1  = (const float*)d_in[5];
    const float* W2  = (const float*)d_in[6];
    const float* b2  = (const float*)d_in[7];
    const int*   nbr = (const int*)d_in[8];
    float* out = (float*)d_out;

    // Single dispatch. 2048 blocks: 256 per batch (16 rows/block),
    // batch = blk & 7 -> XCD pin.
    dim3 grid(B_ * M_ / 16), block(256);
    hipLaunchKernelGGL(it_kernel, grid, block, 0, stream,
                       y, x, f_y, w, W1, b1, W2, b2, nbr, out);
}